// Round 4
// baseline (391.416 us; speedup 1.0000x reference)
//
#include <hip/hip_runtime.h>

#define BATCH 4
#define SQL 2048
#define SKL 2048
#define DIM 512
#define NR 257
#define NRP 288
#define RAD 128

typedef __bf16 bf16x8 __attribute__((ext_vector_type(8)));
typedef float f32x4 __attribute__((ext_vector_type(4)));
typedef unsigned short u16;
typedef u16 u16x4 __attribute__((ext_vector_type(4)));
typedef u16 u16x8 __attribute__((ext_vector_type(8)));

__device__ inline u16 f2bf(float x) {
  union { float f; unsigned u; } v; v.f = x;
  unsigned r = v.u + 0x7FFF + ((v.u >> 16) & 1);   // RNE
  return (u16)(r >> 16);
}

__device__ inline void glds16(const u16* g, const u16* l) {
  __builtin_amdgcn_global_load_lds(
      (const __attribute__((address_space(1))) void*)g,
      (__attribute__((address_space(3))) void*)l, 16, 0, 0);
}

// swizzled LDS byte offsets (XOR bit-4 with row&7): conflict-free ds_read at
// row-strided access, never straddles a 16B sub-block.
#define PSWZ(row, cb) (((row) << 12) + ((cb) ^ (((row) & 7) << 4)))   // P: 4096 B/row
#define QSWZ(row, cb) (((row) << 10) + ((cb) ^ (((row) & 7) << 4)))   // Qs: 1024 B/row

// ---------------- fused memory-only prep (unchanged) ----------------
__global__ __launch_bounds__(256) void prep_mem_kernel(const float* __restrict__ Q,
                                                       const float* __restrict__ K,
                                                       const float* __restrict__ V,
                                                       const float* __restrict__ rel,
                                                       u16x4* __restrict__ Qb,
                                                       u16x4* __restrict__ Kb,
                                                       u16* __restrict__ relb,
                                                       u16* __restrict__ Vt) {
  __shared__ float tile[32][33];
  int bid = blockIdx.x, tid = threadIdx.x;
  if (bid < 8192) {
    const f32x4* src = (bid < 4096) ? (const f32x4*)Q : (const f32x4*)K;
    u16x4* dst = (bid < 4096) ? Qb : Kb;
    int i = (bid & 4095) * 256 + tid;
    f32x4 f = src[i];
    u16x4 o;
#pragma unroll
    for (int e = 0; e < 4; e++) o[e] = f2bf(f[e]);
    dst[i] = o;
  } else if (bid < 8768) {
    int i = (bid - 8192) * 256 + tid;
    int r = i >> 9;
    relb[i] = (r < NR) ? f2bf(rel[i]) : (u16)0;
  } else {
    int t = bid - 8768;
    int b = t >> 10, rem = t & 1023;
    int k0 = (rem & 63) * 32, d0 = (rem >> 6) * 32;
    int tx = tid & 31, ty = tid >> 5;
#pragma unroll
    for (int r = 0; r < 4; r++)
      tile[ty + r * 8][tx] = V[((long)b * SKL + k0 + ty + r * 8) * DIM + d0 + tx];
    __syncthreads();
#pragma unroll
    for (int r = 0; r < 4; r++)
      Vt[((long)b * DIM + d0 + ty + r * 8) * SKL + k0 + tx] = f2bf(tile[tx][ty + r * 8]);
  }
}

// ---------------- Qrel = Q @ rel^T : [8192][NRP] (unchanged) ----------------
__global__ __launch_bounds__(256) void qrel_kernel(const u16* __restrict__ Qb,
                                                   const u16* __restrict__ relb,
                                                   float* __restrict__ Qrel) {
  int tid = threadIdx.x;
  int wave = tid >> 6, lane = tid & 63;
  int m0 = blockIdx.x * 64 + wave * 16;
  int j0 = blockIdx.y * 2;
  int fr = lane & 15, fk = (lane >> 4) * 8;
  f32x4 acc[2] = {};
  const u16* qrow = Qb + (long)(m0 + fr) * DIM + fk;
  const u16* r0 = relb + (long)(j0 * 16 + fr) * DIM + fk;
  const u16* r1 = r0 + 16 * DIM;
  for (int k0 = 0; k0 < DIM; k0 += 32) {
    bf16x8 a = *(const bf16x8*)(qrow + k0);
    bf16x8 b0 = *(const bf16x8*)(r0 + k0);
    bf16x8 b1 = *(const bf16x8*)(r1 + k0);
    acc[0] = __builtin_amdgcn_mfma_f32_16x16x32_bf16(a, b0, acc[0], 0, 0, 0);
    acc[1] = __builtin_amdgcn_mfma_f32_16x16x32_bf16(a, b1, acc[1], 0, 0, 0);
  }
  int cr = (lane >> 4) * 4, cc = lane & 15;
#pragma unroll
  for (int t = 0; t < 2; t++)
#pragma unroll
    for (int r = 0; r < 4; r++)
      Qrel[(long)(m0 + cr + r) * NRP + (j0 + t) * 16 + cc] = acc[t][r];
}

// ---------------- fused attention: QK^T -> softmax(+rel) -> PV ----------------
// One block = 16 Q-rows x one batch. 512 threads (8 waves), 1 block/CU.
// LDS: P 16x2048 bf16 swizzled (64K) + Qs 16x512 bf16 swizzled (16K) + qlds (16.5K).
// Wave w: QK cols [w*256, w*256+256) (16 tiles); PV cols [w*64, w*64+64) (4 tiles).
// Softmax: row r handled by 32 threads = one half-wave -> pure shfl reduction.
__global__ __launch_bounds__(512, 2) void attn_fused_kernel(const u16* __restrict__ Qb,
                                                            const u16* __restrict__ Kb,
                                                            const u16* __restrict__ Vt,
                                                            const float* __restrict__ Qrel,
                                                            float* __restrict__ attn,
                                                            float* __restrict__ Z) {
  __shared__ u16 P[16 * 2048];
  __shared__ u16 Qs[16 * 512];
  __shared__ float qlds[16][264];

  int b = blockIdx.y;
  int m0 = blockIdx.x * 16;
  int tid = threadIdx.x;
  int wave = tid >> 6, lane = tid & 63;
  int fr = lane & 15, fk = (lane >> 4) * 8;
  int cr = (lane >> 4) * 4, cc = lane & 15;
  const float inv_norm = 0.04419417382415922f;  // 1/sqrt(512)

  const u16* Qb_b = Qb + (long)b * SQL * DIM;
  const u16* Kb_b = Kb + (long)b * SKL * DIM;
  const u16* Vt_b = Vt + (long)b * DIM * SKL;

  // ---- stage: Qs (swizzled) + qlds (rel row table, pre-scaled) ----
  {
    int row = tid >> 5, c0 = (tid & 31) * 16;
    const u16* src = Qb_b + (long)(m0 + row) * DIM + c0;
    bf16x8 v0 = *(const bf16x8*)(src);
    bf16x8 v1 = *(const bf16x8*)(src + 8);
    *(bf16x8*)(Qs + (QSWZ(row, c0 * 2) >> 1)) = v0;
    *(bf16x8*)(Qs + (QSWZ(row, c0 * 2 + 16) >> 1)) = v1;
    const float* qr = Qrel + ((long)b * SQL + m0 + row) * NRP;
    for (int j = tid & 31; j < NR; j += 32) qlds[row][j] = qr[j] * inv_norm;
  }
  __syncthreads();

  // ---- phase A: QK^T, 16 n-tiles per wave, K direct from global (L2) ----
  {
    int n0 = wave * 256;
    const u16* Kbw = Kb_b + (long)(n0 + fr) * DIM + fk;
    f32x4 acc[16] = {};
#pragma unroll 4
    for (int k0 = 0; k0 < DIM; k0 += 32) {
      bf16x8 a = *(const bf16x8*)(Qs + (QSWZ(fr, (k0 + fk) * 2) >> 1));
      bf16x8 bb[8];
#pragma unroll
      for (int j = 0; j < 8; j++) bb[j] = *(const bf16x8*)(Kbw + (long)j * 16 * DIM + k0);
#pragma unroll
      for (int j = 0; j < 8; j++)
        acc[j] = __builtin_amdgcn_mfma_f32_16x16x32_bf16(a, bb[j], acc[j], 0, 0, 0);
#pragma unroll
      for (int j = 0; j < 8; j++) bb[j] = *(const bf16x8*)(Kbw + (long)(j + 8) * 16 * DIM + k0);
#pragma unroll
      for (int j = 0; j < 8; j++)
        acc[j + 8] = __builtin_amdgcn_mfma_f32_16x16x32_bf16(a, bb[j], acc[j + 8], 0, 0, 0);
    }
    // epilogue: scaled bf16 logits (no rel) -> swizzled P
#pragma unroll
    for (int j = 0; j < 16; j++) {
      int col = n0 + j * 16 + cc;
#pragma unroll
      for (int r = 0; r < 4; r++) {
        int row = cr + r;
        P[PSWZ(row, col * 2) >> 1] = f2bf(acc[j][r] * inv_norm);
      }
    }
  }
  __syncthreads();

  // ---- phase B/C: row softmax (+rel in fp32), attn write, P -> probs ----
  {
    int s = tid & 31, prow = tid >> 5;
    int q = m0 + prow;
    float* arow = attn + ((long)b * SQL + q) * SKL;
    // pass 1: max
    float mx = -1e30f;
#pragma unroll
    for (int c = 0; c < 16; c++) {
      int col = s * 4 + c * 128;
      u16x4 pv = *(const u16x4*)(P + (PSWZ(prow, col * 2) >> 1));
#pragma unroll
      for (int e = 0; e < 4; e++) {
        int idx = col + e - q + RAD;
        idx = idx < 0 ? 0 : (idx > 2 * RAD ? 2 * RAD : idx);
        union { u16 u[2]; float f; } cv; cv.u[0] = 0; cv.u[1] = pv[e];
        mx = fmaxf(mx, cv.f + qlds[prow][idx]);
      }
    }
#pragma unroll
    for (int o = 1; o <= 16; o <<= 1) mx = fmaxf(mx, __shfl_xor(mx, o));
    // pass 2: sum
    float sum = 0.0f;
#pragma unroll
    for (int c = 0; c < 16; c++) {
      int col = s * 4 + c * 128;
      u16x4 pv = *(const u16x4*)(P + (PSWZ(prow, col * 2) >> 1));
#pragma unroll
      for (int e = 0; e < 4; e++) {
        int idx = col + e - q + RAD;
        idx = idx < 0 ? 0 : (idx > 2 * RAD ? 2 * RAD : idx);
        union { u16 u[2]; float f; } cv; cv.u[0] = 0; cv.u[1] = pv[e];
        sum += __expf(cv.f + qlds[prow][idx] - mx);
      }
    }
#pragma unroll
    for (int o = 1; o <= 16; o <<= 1) sum += __shfl_xor(sum, o);
    float inv = 1.0f / sum;
    // pass 3: write attn fp32 (coalesced 512B segments) + P probs bf16
#pragma unroll
    for (int c = 0; c < 16; c++) {
      int col = s * 4 + c * 128;
      u16x4 pv = *(const u16x4*)(P + (PSWZ(prow, col * 2) >> 1));
      f32x4 o4;
      u16x4 pb;
#pragma unroll
      for (int e = 0; e < 4; e++) {
        int idx = col + e - q + RAD;
        idx = idx < 0 ? 0 : (idx > 2 * RAD ? 2 * RAD : idx);
        union { u16 u[2]; float f; } cv; cv.u[0] = 0; cv.u[1] = pv[e];
        float p = __expf(cv.f + qlds[prow][idx] - mx) * inv;
        o4[e] = p; pb[e] = f2bf(p);
      }
      *(f32x4*)(arow + col) = o4;
      *(u16x4*)(P + (PSWZ(prow, col * 2) >> 1)) = pb;
    }
  }
  __syncthreads();

  // ---- phase D: PV, 4 n-tiles per wave, Vt direct from global (L2) ----
  {
    int wn = wave * 64;
    const u16* Vw = Vt_b + (long)(wn + fr) * SKL + fk;
    f32x4 acc2[4] = {};
#pragma unroll 2
    for (int k0 = 0; k0 < SKL; k0 += 32) {
      bf16x8 a = *(const bf16x8*)(P + (PSWZ(fr, (k0 + fk) * 2) >> 1));
#pragma unroll
      for (int j = 0; j < 4; j++) {
        bf16x8 bv = *(const bf16x8*)(Vw + (long)j * 16 * SKL + k0);
        acc2[j] = __builtin_amdgcn_mfma_f32_16x16x32_bf16(a, bv, acc2[j], 0, 0, 0);
      }
    }
#pragma unroll
    for (int j = 0; j < 4; j++)
#pragma unroll
      for (int r = 0; r < 4; r++)
        Z[((long)b * SQL + m0 + cr + r) * DIM + wn + j * 16 + cc] = acc2[j][r];
  }
}

// ---------------- launch ----------------

extern "C" void kernel_launch(void* const* d_in, const int* in_sizes, int n_in,
                              void* d_out, int out_size, void* d_ws, size_t ws_size,
                              hipStream_t stream) {
  const float* Q = (const float*)d_in[0];
  const float* K = (const float*)d_in[1];
  const float* V = (const float*)d_in[2];
  const float* rel = (const float*)d_in[3];
  float* attn = (float*)d_out;                       // [4][2048][2048]
  float* Z = attn + (long)BATCH * SQL * SKL;         // [4][2048][512]

  char* ws = (char*)d_ws;
  u16* Qb   = (u16*)ws;                    //  8 MiB  bf16 Q [b][q][d]
  u16* Kb   = (u16*)(ws + 8388608);        //  8 MiB  bf16 K [b][k][d]
  u16* Vt   = (u16*)(ws + 16777216);       //  8 MiB  bf16 V^T [b][d][k]
  u16* relb = (u16*)(ws + 25165824);       //  288 KiB bf16 rel padded [288][512]
  float* Qrel = (float*)(ws + 25460736);   //  9 MiB  fp32 Qrel [8192][288]

  prep_mem_kernel<<<12864, 256, 0, stream>>>(Q, K, V, rel, (u16x4*)Qb, (u16x4*)Kb, relb, Vt);
  qrel_kernel<<<dim3(128, 9), 256, 0, stream>>>(Qb, relb, Qrel);
  attn_fused_kernel<<<dim3(128, BATCH), 512, 0, stream>>>(Qb, Kb, Vt, Qrel, attn, Z);
}

// Round 5
// 225.098 us; speedup vs baseline: 1.7389x; 1.7389x over previous
//
#include <hip/hip_runtime.h>

#define BATCH 4
#define SQL 2048
#define SKL 2048
#define DIM 512
#define NR 257
#define NRP 288
#define RAD 128

typedef __bf16 bf16x8 __attribute__((ext_vector_type(8)));
typedef float f32x4 __attribute__((ext_vector_type(4)));
typedef unsigned short u16;
typedef u16 u16x4 __attribute__((ext_vector_type(4)));
typedef u16 u16x8 __attribute__((ext_vector_type(8)));

__device__ inline u16 f2bf(float x) {
  union { float f; unsigned u; } v; v.f = x;
  unsigned r = v.u + 0x7FFF + ((v.u >> 16) & 1);   // RNE
  return (u16)(r >> 16);
}

__device__ inline void glds16(const u16* g, const u16* l) {
  __builtin_amdgcn_global_load_lds(
      (const __attribute__((address_space(1))) void*)g,
      (__attribute__((address_space(3))) void*)l, 16, 0, 0);
}

// ---------------- fused memory-only prep ----------------
__global__ __launch_bounds__(256) void prep_mem_kernel(const float* __restrict__ Q,
                                                       const float* __restrict__ K,
                                                       const float* __restrict__ V,
                                                       const float* __restrict__ rel,
                                                       u16x4* __restrict__ Qb,
                                                       u16x4* __restrict__ Kb,
                                                       u16* __restrict__ relb,
                                                       u16* __restrict__ Vt) {
  __shared__ float tile[32][33];
  int bid = blockIdx.x, tid = threadIdx.x;
  if (bid < 8192) {
    const f32x4* src = (bid < 4096) ? (const f32x4*)Q : (const f32x4*)K;
    u16x4* dst = (bid < 4096) ? Qb : Kb;
    int i = (bid & 4095) * 256 + tid;     // exactly covers 1048576 f32x4
    f32x4 f = src[i];
    u16x4 o;
#pragma unroll
    for (int e = 0; e < 4; e++) o[e] = f2bf(f[e]);
    dst[i] = o;
  } else if (bid < 8768) {
    int i = (bid - 8192) * 256 + tid;     // < NRP*DIM
    int r = i >> 9;                       // / 512
    relb[i] = (r < NR) ? f2bf(rel[i]) : (u16)0;
  } else {
    int t = bid - 8768;
    int b = t >> 10, rem = t & 1023;
    int k0 = (rem & 63) * 32, d0 = (rem >> 6) * 32;
    int tx = tid & 31, ty = tid >> 5;     // 32 x 8
#pragma unroll
    for (int r = 0; r < 4; r++)
      tile[ty + r * 8][tx] = V[((long)b * SKL + k0 + ty + r * 8) * DIM + d0 + tx];
    __syncthreads();
#pragma unroll
    for (int r = 0; r < 4; r++)
      Vt[((long)b * DIM + d0 + ty + r * 8) * SKL + k0 + tx] = f2bf(tile[tx][ty + r * 8]);
  }
}

// ---------------- Qrel = Q @ rel^T : [8192][NRP] ----------------
__global__ __launch_bounds__(256) void qrel_kernel(const u16* __restrict__ Qb,
                                                   const u16* __restrict__ relb,
                                                   float* __restrict__ Qrel) {
  int tid = threadIdx.x;
  int wave = tid >> 6, lane = tid & 63;
  int m0 = blockIdx.x * 64 + wave * 16;
  int j0 = blockIdx.y * 2;                 // col tiles j0, j0+1
  int fr = lane & 15, fk = (lane >> 4) * 8;
  f32x4 acc[2] = {};
  const u16* qrow = Qb + (long)(m0 + fr) * DIM + fk;
  const u16* r0 = relb + (long)(j0 * 16 + fr) * DIM + fk;
  const u16* r1 = r0 + 16 * DIM;
  for (int k0 = 0; k0 < DIM; k0 += 32) {
    bf16x8 a = *(const bf16x8*)(qrow + k0);
    bf16x8 b0 = *(const bf16x8*)(r0 + k0);
    bf16x8 b1 = *(const bf16x8*)(r1 + k0);
    acc[0] = __builtin_amdgcn_mfma_f32_16x16x32_bf16(a, b0, acc[0], 0, 0, 0);
    acc[1] = __builtin_amdgcn_mfma_f32_16x16x32_bf16(a, b1, acc[1], 0, 0, 0);
  }
  int cr = (lane >> 4) * 4, cc = lane & 15;
#pragma unroll
  for (int t = 0; t < 2; t++)
#pragma unroll
    for (int r = 0; r < 4; r++)
      Qrel[(long)(m0 + cr + r) * NRP + (j0 + t) * 16 + cc] = acc[t][r];
}

// ---------------- energy: S = bf16(Q K^T / sqrt(d)) ----------------
// 256x256 tile, 8 waves (2M x 4N, each 128x64 out), BK=64, double-buffered
// 128 KiB LDS, 4-phase counted-vmcnt schedule (T2+T3+T4+T5):
//  phase 1: stage A(t+1).c3 + B(t+1) -> idle slot; load B regs; quad 0
//  phase q (2..4): stage A(t+2).c(q-2) into rows of CURRENT slot freed by
//                  quad q-2's barrier; quad q-1
//  tile end: s_waitcnt vmcnt(3)  (A(t+2) chunks stay in flight), s_barrier
// LDS logical (row, colbyte cb) at row*128 + (cb ^ ((row&7)<<4)); glds16 dest
// linear -> source col inverse-swizzled (same proven pair as r3).
__global__ __launch_bounds__(512, 2) void energy_kernel(const u16* __restrict__ Qb,
                                                        const u16* __restrict__ Kb,
                                                        u16* __restrict__ S) {
  __shared__ u16 lds[65536];            // 128 KiB: [slot][A 16384 u16 | B 16384 u16]
  int b = blockIdx.z;
  int m0 = blockIdx.y * 256, n0 = blockIdx.x * 256;
  const u16* A = Qb + (long)b * SQL * DIM;
  const u16* Bp = Kb + (long)b * SKL * DIM;
  int tid = threadIdx.x;
  int wave = tid >> 6, lane = tid & 63;
  int wr = wave >> 2, wc = wave & 3;
  int fr = lane & 15, g = lane >> 4;
  int srow8 = lane >> 3;
  int scol = ((lane & 7) ^ srow8) * 8;  // inverse-swizzled source col (elems)

  f32x4 acc[4][2][4] = {};
  bf16x8 bB[4][2];

#define STA(slot, tt, q) do { \
    int rb_ = (q) * 32 + (wave & 3) * 8 + (wave >> 2) * 128; \
    glds16(A + (long)(m0 + rb_ + srow8) * DIM + (tt) * 64 + scol, \
           lds + (slot) * 32768 + rb_ * 64); \
  } while (0)
#define STB(slot, tt, p) do { \
    int rb_ = (p) * 64 + wave * 8; \
    glds16(Bp + (long)(n0 + rb_ + srow8) * DIM + (tt) * 64 + scol, \
           lds + (slot) * 32768 + 16384 + rb_ * 64); \
  } while (0)
#define LOADB(slot) do { \
    const u16* base_ = lds + (slot) * 32768 + 16384; \
    _Pragma("unroll") for (int jb = 0; jb < 4; jb++) { \
      _Pragma("unroll") for (int ks = 0; ks < 2; ks++) { \
        int row_ = wc * 64 + jb * 16 + fr; \
        int cb_ = (ks * 64 + g * 16) ^ ((row_ & 7) << 4); \
        bB[jb][ks] = *(const bf16x8*)(base_ + row_ * 64 + (cb_ >> 1)); \
      } \
    } \
  } while (0)
#define QUAD(slot, q) do { \
    const u16* baseA_ = lds + (slot) * 32768; \
    bf16x8 a_[2][2]; \
    _Pragma("unroll") for (int rb = 0; rb < 2; rb++) { \
      _Pragma("unroll") for (int ks = 0; ks < 2; ks++) { \
        int row_ = wr * 128 + (q) * 32 + rb * 16 + fr; \
        int cb_ = (ks * 64 + g * 16) ^ ((row_ & 7) << 4); \
        a_[rb][ks] = *(const bf16x8*)(baseA_ + row_ * 64 + (cb_ >> 1)); \
      } \
    } \
    __builtin_amdgcn_s_setprio(1); \
    _Pragma("unroll") for (int rb = 0; rb < 2; rb++) \
    _Pragma("unroll") for (int jb = 0; jb < 4; jb++) \
    _Pragma("unroll") for (int ks = 0; ks < 2; ks++) \
      acc[q][rb][jb] = __builtin_amdgcn_mfma_f32_16x16x32_bf16(a_[rb][ks], bB[jb][ks], acc[q][rb][jb], 0, 0, 0); \
    __builtin_amdgcn_s_setprio(0); \
  } while (0)

  const int NT = DIM / 64;  // 8
  // prologue: tile 0 complete + A(1) chunks 0..2 left in flight
  STA(0, 0, 0); STA(0, 0, 1); STA(0, 0, 2); STA(0, 0, 3);
  STB(0, 0, 0); STB(0, 0, 1); STB(0, 0, 2); STB(0, 0, 3);
  STA(1, 1, 0); STA(1, 1, 1); STA(1, 1, 2);
  asm volatile("s_waitcnt vmcnt(3)" ::: "memory");
  asm volatile("s_barrier" ::: "memory");

  for (int t = 0; t < NT; ++t) {
    int cs = t & 1, ns = cs ^ 1;
    // ---- phase 1 ----
    if (t + 1 < NT) {
      STA(ns, t + 1, 3);
      STB(ns, t + 1, 0); STB(ns, t + 1, 1); STB(ns, t + 1, 2); STB(ns, t + 1, 3);
    }
    LOADB(cs);
    QUAD(cs, 0);
    asm volatile("s_barrier" ::: "memory");
    // ---- phase 2 ----
    if (t + 2 < NT) STA(cs, t + 2, 0);
    QUAD(cs, 1);
    asm volatile("s_barrier" ::: "memory");
    // ---- phase 3 ----
    if (t + 2 < NT) STA(cs, t + 2, 1);
    QUAD(cs, 2);
    asm volatile("s_barrier" ::: "memory");
    // ---- phase 4 ----
    if (t + 2 < NT) STA(cs, t + 2, 2);
    QUAD(cs, 3);
    if (t + 2 < NT) asm volatile("s_waitcnt vmcnt(3)" ::: "memory");
    else            asm volatile("s_waitcnt vmcnt(0)" ::: "memory");
    asm volatile("s_barrier" ::: "memory");
  }
#undef STA
#undef STB
#undef LOADB
#undef QUAD

  const float inv_norm = 0.04419417382415922f;  // 1/sqrt(512)
  int cr = (lane >> 4) * 4, cc = lane & 15;
#pragma unroll
  for (int q = 0; q < 4; q++)
#pragma unroll
    for (int rb = 0; rb < 2; rb++)
#pragma unroll
      for (int r = 0; r < 4; r++) {
        int row = m0 + wr * 128 + q * 32 + rb * 16 + cr + r;
        u16* sr = S + ((long)b * SQL + row) * SKL;
#pragma unroll
        for (int jb = 0; jb < 4; jb++)
          sr[n0 + wc * 64 + jb * 16 + cc] = f2bf(acc[q][rb][jb][r] * inv_norm);
      }
}

// ---------------- softmax: logits + rel gather -> fp32 attn + bf16 probs (S in-place) ----
__global__ __launch_bounds__(256) void softmax_kernel(u16* __restrict__ S,
                                                      const float* __restrict__ Qrel,
                                                      float* __restrict__ attn) {
  long row = blockIdx.x;
  int q = (int)(row & (SQL - 1));
  u16* srow = S + row * SKL;
  float* arow = attn + row * SKL;
  int tid = threadIdx.x;
  int wave = tid >> 6, lane = tid & 63;
  __shared__ float qlds[NR];
  __shared__ float red[4];
  const float inv_norm = 0.04419417382415922f;
  const float* qr = Qrel + row * NRP;
  qlds[tid] = qr[tid] * inv_norm;          // tid 0..255
  if (tid == 0) qlds[256] = qr[256] * inv_norm;
  bf16x8 v = *(const bf16x8*)(srow + tid * 8);
  __syncthreads();
  float f[8];
  int kb = tid * 8 - q + RAD;
#pragma unroll
  for (int e = 0; e < 8; e++) {
    int idx = kb + e;
    idx = idx < 0 ? 0 : (idx > 2 * RAD ? 2 * RAD : idx);
    f[e] = (float)v[e] + qlds[idx];
  }
  float m = -1e30f;
#pragma unroll
  for (int e = 0; e < 8; e++) m = fmaxf(m, f[e]);
  for (int o = 32; o > 0; o >>= 1) m = fmaxf(m, __shfl_xor(m, o));
  if (lane == 0) red[wave] = m;
  __syncthreads();
  m = fmaxf(fmaxf(red[0], red[1]), fmaxf(red[2], red[3]));
  __syncthreads();
  float s = 0.0f;
  float e8[8];
#pragma unroll
  for (int e = 0; e < 8; e++) { e8[e] = __expf(f[e] - m); s += e8[e]; }
  for (int o = 32; o > 0; o >>= 1) s += __shfl_xor(s, o);
  if (lane == 0) red[wave] = s;
  __syncthreads();
  s = red[0] + red[1] + red[2] + red[3];
  float inv = 1.0f / s;
  f32x4 o0, o1;
  u16x8 pb;
#pragma unroll
  for (int e = 0; e < 4; e++) {
    float p = e8[e] * inv;
    o0[e] = p; pb[e] = f2bf(p);
  }
#pragma unroll
  for (int e = 0; e < 4; e++) {
    float p = e8[e + 4] * inv;
    o1[e] = p; pb[e + 4] = f2bf(p);
  }
  *(f32x4*)(arow + tid * 8) = o0;
  *(f32x4*)(arow + tid * 8 + 4) = o1;
  *(u16x8*)(srow + tid * 8) = pb;
}

// ---------------- Z = P @ V  (P = bf16 probs in S; Vt is [b][d][k] bf16) ----------------
// 64x128 tile (M x N), 4 waves (2x2 of 32x64), BK=64, double-buffered LDS,
// 2-phase pipeline + T2 XOR swizzle.
__global__ __launch_bounds__(256) void z_kernel(const u16* __restrict__ S,
                                                const u16* __restrict__ Vt,
                                                float* __restrict__ Z) {
  int b = blockIdx.z;
  int m0 = blockIdx.y * 64;
  int n0 = blockIdx.x * 128;
  const u16* A = S + (long)b * SQL * SKL;
  const u16* Bp = Vt + (long)b * DIM * SKL;
  __shared__ u16 lds[24576];               // 48 KiB: As0(4096)|Bs0(8192)|As1|Bs1
  u16* As0 = lds;          u16* Bs0 = lds + 4096;
  u16* As1 = lds + 12288;  u16* Bs1 = lds + 16384;
  int tid = threadIdx.x;
  int wave = tid >> 6, lane = tid & 63;
  int wm = (wave >> 1) * 32, wn = (wave & 1) * 64;
  int fr = lane & 15, g = lane >> 4;
  int srow = lane >> 3;
  int scol = ((lane & 7) ^ srow) * 8;
  f32x4 acc[2][4] = {};

  auto stage = [&](u16* dA, u16* dB, int k0) {
#pragma unroll
    for (int c = 0; c < 2; c++) {
      int r = wave * 16 + c * 8;
      glds16(A + (long)(m0 + r + srow) * SKL + k0 + scol, dA + r * 64);
    }
#pragma unroll
    for (int c = 0; c < 4; c++) {
      int r = wave * 32 + c * 8;
      glds16(Bp + (long)(n0 + r + srow) * SKL + k0 + scol, dB + r * 64);
    }
  };
  auto compute = [&](const u16* Asb, const u16* Bsb) {
#pragma unroll
    for (int s = 0; s < 2; s++) {
      bf16x8 af[2], bfv[4];
#pragma unroll
      for (int i = 0; i < 2; i++) {
        int row = wm + i * 16 + fr;
        int cb = (s * 64 + g * 16) ^ ((row & 7) << 4);
        af[i] = *(const bf16x8*)(Asb + row * 64 + (cb >> 1));
      }
#pragma unroll
      for (int j = 0; j < 4; j++) {
        int row = wn + j * 16 + fr;
        int cb = (s * 64 + g * 16) ^ ((row & 7) << 4);
        bfv[j] = *(const bf16x8*)(Bsb + row * 64 + (cb >> 1));
      }
#pragma unroll
      for (int i = 0; i < 2; i++)
#pragma unroll
        for (int j = 0; j < 4; j++)
          acc[i][j] = __builtin_amdgcn_mfma_f32_16x16x32_bf16(af[i], bfv[j], acc[i][j], 0, 0, 0);
    }
  };

  const int NT = SKL / 64;                 // 32
  stage(As0, Bs0, 0);
  __syncthreads();
  for (int t = 0; t < NT; t += 2) {
    if (t + 1 < NT) stage(As1, Bs1, (t + 1) * 64);
    compute(As0, Bs0);
    __syncthreads();
    if (t + 1 < NT) {
      if (t + 2 < NT) stage(As0, Bs0, (t + 2) * 64);
      compute(As1, Bs1);
      __syncthreads();
    }
  }

  int cr = (lane >> 4) * 4, cc = lane & 15;
#pragma unroll
  for (int i = 0; i < 2; i++)
#pragma unroll
    for (int r = 0; r < 4; r++) {
      int q = m0 + wm + i * 16 + cr + r;
      float* zrow = Z + ((long)b * SQL + q) * DIM;
#pragma unroll
      for (int j = 0; j < 4; j++)
        zrow[n0 + wn + j * 16 + cc] = acc[i][j][r];
    }
}

// ---------------- launch ----------------

extern "C" void kernel_launch(void* const* d_in, const int* in_sizes, int n_in,
                              void* d_out, int out_size, void* d_ws, size_t ws_size,
                              hipStream_t stream) {
  const float* Q = (const float*)d_in[0];
  const float* K = (const float*)d_in[1];
  const float* V = (const float*)d_in[2];
  const float* rel = (const float*)d_in[3];
  float* attn = (float*)d_out;                       // [4][2048][2048]
  float* Z = attn + (long)BATCH * SQL * SKL;         // [4][2048][512]

  char* ws = (char*)d_ws;
  u16* Qb   = (u16*)ws;                    //  8 MiB  bf16 Q [b][q][d]
  u16* Kb   = (u16*)(ws + 8388608);        //  8 MiB  bf16 K [b][k][d]
  u16* Vt   = (u16*)(ws + 16777216);       //  8 MiB  bf16 V^T [b][d][k]
  u16* relb = (u16*)(ws + 25165824);       //  288 KiB bf16 rel padded [288][512]
  float* Qrel = (float*)(ws + 25460736);   //  9 MiB  fp32 Qrel [8192][288]
  u16* S    = (u16*)(ws + 34897920);       //  32 MiB bf16 scores/probs [b][q][k]

  prep_mem_kernel<<<12864, 256, 0, stream>>>(Q, K, V, rel, (u16x4*)Qb, (u16x4*)Kb, relb, Vt);
  qrel_kernel<<<dim3(128, 9), 256, 0, stream>>>(Qb, relb, Qrel);
  energy_kernel<<<dim3(8, 8, BATCH), 512, 0, stream>>>(Qb, Kb, S);
  softmax_kernel<<<8192, 256, 0, stream>>>(S, Qrel, attn);
  z_kernel<<<dim3(4, 32, BATCH), 256, 0, stream>>>(S, Vt, Z);
}

// Round 6
// 216.645 us; speedup vs baseline: 1.8067x; 1.0390x over previous
//
#include <hip/hip_runtime.h>

#define BATCH 4
#define SQL 2048
#define SKL 2048
#define DIM 512
#define NR 257
#define NRP 288
#define RAD 128

typedef __bf16 bf16x8 __attribute__((ext_vector_type(8)));
typedef float f32x4 __attribute__((ext_vector_type(4)));
typedef unsigned short u16;
typedef u16 u16x4 __attribute__((ext_vector_type(4)));
typedef u16 u16x8 __attribute__((ext_vector_type(8)));

__device__ inline u16 f2bf(float x) {
  union { float f; unsigned u; } v; v.f = x;
  unsigned r = v.u + 0x7FFF + ((v.u >> 16) & 1);   // RNE
  return (u16)(r >> 16);
}

__device__ inline void glds16(const u16* g, const u16* l) {
  __builtin_amdgcn_global_load_lds(
      (const __attribute__((address_space(1))) void*)g,
      (__attribute__((address_space(3))) void*)l, 16, 0, 0);
}

// ---------------- fused memory-only prep ----------------
__global__ __launch_bounds__(256) void prep_mem_kernel(const float* __restrict__ Q,
                                                       const float* __restrict__ K,
                                                       const float* __restrict__ V,
                                                       const float* __restrict__ rel,
                                                       u16x4* __restrict__ Qb,
                                                       u16x4* __restrict__ Kb,
                                                       u16* __restrict__ relb,
                                                       u16* __restrict__ Vt) {
  __shared__ float tile[32][33];
  int bid = blockIdx.x, tid = threadIdx.x;
  if (bid < 8192) {
    const f32x4* src = (bid < 4096) ? (const f32x4*)Q : (const f32x4*)K;
    u16x4* dst = (bid < 4096) ? Qb : Kb;
    int i = (bid & 4095) * 256 + tid;     // exactly covers 1048576 f32x4
    f32x4 f = src[i];
    u16x4 o;
#pragma unroll
    for (int e = 0; e < 4; e++) o[e] = f2bf(f[e]);
    dst[i] = o;
  } else if (bid < 8768) {
    int i = (bid - 8192) * 256 + tid;     // < NRP*DIM
    int r = i >> 9;                       // / 512
    relb[i] = (r < NR) ? f2bf(rel[i]) : (u16)0;
  } else {
    int t = bid - 8768;
    int b = t >> 10, rem = t & 1023;
    int k0 = (rem & 63) * 32, d0 = (rem >> 6) * 32;
    int tx = tid & 31, ty = tid >> 5;     // 32 x 8
#pragma unroll
    for (int r = 0; r < 4; r++)
      tile[ty + r * 8][tx] = V[((long)b * SKL + k0 + ty + r * 8) * DIM + d0 + tx];
    __syncthreads();
#pragma unroll
    for (int r = 0; r < 4; r++)
      Vt[((long)b * DIM + d0 + ty + r * 8) * SKL + k0 + tx] = f2bf(tile[tx][ty + r * 8]);
  }
}

// ---------------- Qrel = Q @ rel^T : [8192][NRP] ----------------
__global__ __launch_bounds__(256) void qrel_kernel(const u16* __restrict__ Qb,
                                                   const u16* __restrict__ relb,
                                                   float* __restrict__ Qrel) {
  int tid = threadIdx.x;
  int wave = tid >> 6, lane = tid & 63;
  int m0 = blockIdx.x * 64 + wave * 16;
  int j0 = blockIdx.y * 2;                 // col tiles j0, j0+1
  int fr = lane & 15, fk = (lane >> 4) * 8;
  f32x4 acc[2] = {};
  const u16* qrow = Qb + (long)(m0 + fr) * DIM + fk;
  const u16* r0 = relb + (long)(j0 * 16 + fr) * DIM + fk;
  const u16* r1 = r0 + 16 * DIM;
  for (int k0 = 0; k0 < DIM; k0 += 32) {
    bf16x8 a = *(const bf16x8*)(qrow + k0);
    bf16x8 b0 = *(const bf16x8*)(r0 + k0);
    bf16x8 b1 = *(const bf16x8*)(r1 + k0);
    acc[0] = __builtin_amdgcn_mfma_f32_16x16x32_bf16(a, b0, acc[0], 0, 0, 0);
    acc[1] = __builtin_amdgcn_mfma_f32_16x16x32_bf16(a, b1, acc[1], 0, 0, 0);
  }
  int cr = (lane >> 4) * 4, cc = lane & 15;
#pragma unroll
  for (int t = 0; t < 2; t++)
#pragma unroll
    for (int r = 0; r < 4; r++)
      Qrel[(long)(m0 + cr + r) * NRP + (j0 + t) * 16 + cc] = acc[t][r];
}

// ---------------- energy: S = bf16(Q K^T / sqrt(d)) (unchanged from r5) ----------------
__global__ __launch_bounds__(512, 2) void energy_kernel(const u16* __restrict__ Qb,
                                                        const u16* __restrict__ Kb,
                                                        u16* __restrict__ S) {
  __shared__ u16 lds[65536];            // 128 KiB: [slot][A 16384 u16 | B 16384 u16]
  int b = blockIdx.z;
  int m0 = blockIdx.y * 256, n0 = blockIdx.x * 256;
  const u16* A = Qb + (long)b * SQL * DIM;
  const u16* Bp = Kb + (long)b * SKL * DIM;
  int tid = threadIdx.x;
  int wave = tid >> 6, lane = tid & 63;
  int wr = wave >> 2, wc = wave & 3;
  int fr = lane & 15, g = lane >> 4;
  int srow8 = lane >> 3;
  int scol = ((lane & 7) ^ srow8) * 8;  // inverse-swizzled source col (elems)

  f32x4 acc[4][2][4] = {};
  bf16x8 bB[4][2];

#define STA(slot, tt, q) do { \
    int rb_ = (q) * 32 + (wave & 3) * 8 + (wave >> 2) * 128; \
    glds16(A + (long)(m0 + rb_ + srow8) * DIM + (tt) * 64 + scol, \
           lds + (slot) * 32768 + rb_ * 64); \
  } while (0)
#define STB(slot, tt, p) do { \
    int rb_ = (p) * 64 + wave * 8; \
    glds16(Bp + (long)(n0 + rb_ + srow8) * DIM + (tt) * 64 + scol, \
           lds + (slot) * 32768 + 16384 + rb_ * 64); \
  } while (0)
#define LOADB(slot) do { \
    const u16* base_ = lds + (slot) * 32768 + 16384; \
    _Pragma("unroll") for (int jb = 0; jb < 4; jb++) { \
      _Pragma("unroll") for (int ks = 0; ks < 2; ks++) { \
        int row_ = wc * 64 + jb * 16 + fr; \
        int cb_ = (ks * 64 + g * 16) ^ ((row_ & 7) << 4); \
        bB[jb][ks] = *(const bf16x8*)(base_ + row_ * 64 + (cb_ >> 1)); \
      } \
    } \
  } while (0)
#define QUAD(slot, q) do { \
    const u16* baseA_ = lds + (slot) * 32768; \
    bf16x8 a_[2][2]; \
    _Pragma("unroll") for (int rb = 0; rb < 2; rb++) { \
      _Pragma("unroll") for (int ks = 0; ks < 2; ks++) { \
        int row_ = wr * 128 + (q) * 32 + rb * 16 + fr; \
        int cb_ = (ks * 64 + g * 16) ^ ((row_ & 7) << 4); \
        a_[rb][ks] = *(const bf16x8*)(baseA_ + row_ * 64 + (cb_ >> 1)); \
      } \
    } \
    __builtin_amdgcn_s_setprio(1); \
    _Pragma("unroll") for (int rb = 0; rb < 2; rb++) \
    _Pragma("unroll") for (int jb = 0; jb < 4; jb++) \
    _Pragma("unroll") for (int ks = 0; ks < 2; ks++) \
      acc[q][rb][jb] = __builtin_amdgcn_mfma_f32_16x16x32_bf16(a_[rb][ks], bB[jb][ks], acc[q][rb][jb], 0, 0, 0); \
    __builtin_amdgcn_s_setprio(0); \
  } while (0)

  const int NT = DIM / 64;  // 8
  STA(0, 0, 0); STA(0, 0, 1); STA(0, 0, 2); STA(0, 0, 3);
  STB(0, 0, 0); STB(0, 0, 1); STB(0, 0, 2); STB(0, 0, 3);
  STA(1, 1, 0); STA(1, 1, 1); STA(1, 1, 2);
  asm volatile("s_waitcnt vmcnt(3)" ::: "memory");
  asm volatile("s_barrier" ::: "memory");

  for (int t = 0; t < NT; ++t) {
    int cs = t & 1, ns = cs ^ 1;
    if (t + 1 < NT) {
      STA(ns, t + 1, 3);
      STB(ns, t + 1, 0); STB(ns, t + 1, 1); STB(ns, t + 1, 2); STB(ns, t + 1, 3);
    }
    LOADB(cs);
    QUAD(cs, 0);
    asm volatile("s_barrier" ::: "memory");
    if (t + 2 < NT) STA(cs, t + 2, 0);
    QUAD(cs, 1);
    asm volatile("s_barrier" ::: "memory");
    if (t + 2 < NT) STA(cs, t + 2, 1);
    QUAD(cs, 2);
    asm volatile("s_barrier" ::: "memory");
    if (t + 2 < NT) STA(cs, t + 2, 2);
    QUAD(cs, 3);
    if (t + 2 < NT) asm volatile("s_waitcnt vmcnt(3)" ::: "memory");
    else            asm volatile("s_waitcnt vmcnt(0)" ::: "memory");
    asm volatile("s_barrier" ::: "memory");
  }
#undef STA
#undef STB
#undef LOADB
#undef QUAD

  const float inv_norm = 0.04419417382415922f;  // 1/sqrt(512)
  int cr = (lane >> 4) * 4, cc = lane & 15;
#pragma unroll
  for (int q = 0; q < 4; q++)
#pragma unroll
    for (int rb = 0; rb < 2; rb++)
#pragma unroll
      for (int r = 0; r < 4; r++) {
        int row = m0 + wr * 128 + q * 32 + rb * 16 + cr + r;
        u16* sr = S + ((long)b * SQL + row) * SKL;
#pragma unroll
        for (int jb = 0; jb < 4; jb++)
          sr[n0 + wc * 64 + jb * 16 + cc] = f2bf(acc[q][rb][jb][r] * inv_norm);
      }
}

// ---------------- softmax (unchanged) ----------------
__global__ __launch_bounds__(256) void softmax_kernel(u16* __restrict__ S,
                                                      const float* __restrict__ Qrel,
                                                      float* __restrict__ attn) {
  long row = blockIdx.x;
  int q = (int)(row & (SQL - 1));
  u16* srow = S + row * SKL;
  float* arow = attn + row * SKL;
  int tid = threadIdx.x;
  int wave = tid >> 6, lane = tid & 63;
  __shared__ float qlds[NR];
  __shared__ float red[4];
  const float inv_norm = 0.04419417382415922f;
  const float* qr = Qrel + row * NRP;
  qlds[tid] = qr[tid] * inv_norm;          // tid 0..255
  if (tid == 0) qlds[256] = qr[256] * inv_norm;
  bf16x8 v = *(const bf16x8*)(srow + tid * 8);
  __syncthreads();
  float f[8];
  int kb = tid * 8 - q + RAD;
#pragma unroll
  for (int e = 0; e < 8; e++) {
    int idx = kb + e;
    idx = idx < 0 ? 0 : (idx > 2 * RAD ? 2 * RAD : idx);
    f[e] = (float)v[e] + qlds[idx];
  }
  float m = -1e30f;
#pragma unroll
  for (int e = 0; e < 8; e++) m = fmaxf(m, f[e]);
  for (int o = 32; o > 0; o >>= 1) m = fmaxf(m, __shfl_xor(m, o));
  if (lane == 0) red[wave] = m;
  __syncthreads();
  m = fmaxf(fmaxf(red[0], red[1]), fmaxf(red[2], red[3]));
  __syncthreads();
  float s = 0.0f;
  float e8[8];
#pragma unroll
  for (int e = 0; e < 8; e++) { e8[e] = __expf(f[e] - m); s += e8[e]; }
  for (int o = 32; o > 0; o >>= 1) s += __shfl_xor(s, o);
  if (lane == 0) red[wave] = s;
  __syncthreads();
  s = red[0] + red[1] + red[2] + red[3];
  float inv = 1.0f / s;
  f32x4 o0, o1;
  u16x8 pb;
#pragma unroll
  for (int e = 0; e < 4; e++) {
    float p = e8[e] * inv;
    o0[e] = p; pb[e] = f2bf(p);
  }
#pragma unroll
  for (int e = 0; e < 4; e++) {
    float p = e8[e + 4] * inv;
    o1[e] = p; pb[e + 4] = f2bf(p);
  }
  *(f32x4*)(arow + tid * 8) = o0;
  *(f32x4*)(arow + tid * 8 + 4) = o1;
  *(u16x8*)(srow + tid * 8) = pb;
}

// ---------------- Z = P @ V  (P = bf16 probs in S; Vt is [b][d][k] bf16) ----------------
// 128x128 tile, 8 waves (2M x 4N, each 64x32 out), BK=64, NT=32, 64 KiB LDS dbuf.
// All frags register-buffered at tile-top -> 2-barrier/tile 2-deep pipeline:
//   read cs frags; lgkmcnt(0); barrier  (cs LDS now dead for all waves)
//   stage t+2 -> cs (4 glds16/wave)
//   16 MFMA
//   vmcnt(4)  (t+1's stages complete; t+2's 4 stay in flight); barrier
// Same proven swizzle pair as energy. 2 blocks/CU via __launch_bounds__(512,4).
__global__ __launch_bounds__(512, 4) void z_kernel(const u16* __restrict__ S,
                                                   const u16* __restrict__ Vt,
                                                   float* __restrict__ Z) {
  __shared__ u16 lds[32768];            // 64 KiB: [slot 16384 u16][A 8192 | B 8192]
  int b = blockIdx.z;
  int m0 = blockIdx.y * 128;            // 16
  int n0 = blockIdx.x * 128;            // 4
  const u16* A = S + (long)b * SQL * SKL;
  const u16* Bp = Vt + (long)b * DIM * SKL;
  int tid = threadIdx.x;
  int wave = tid >> 6, lane = tid & 63;
  int wr = wave >> 2, wc = wave & 3;    // wave out: rows wr*64..+64, cols wc*32..+32
  int fr = lane & 15, g = lane >> 4;
  int srow8 = lane >> 3;
  int scol = ((lane & 7) ^ srow8) * 8;

  f32x4 acc[4][2] = {};

#define ZSTG(slot, tt) do { \
    _Pragma("unroll") for (int i_ = 0; i_ < 2; i_++) { \
      int r_ = wave * 16 + i_ * 8; \
      glds16(A + (long)(m0 + r_ + srow8) * SKL + (tt) * 64 + scol, \
             lds + (slot) * 16384 + r_ * 64); \
      glds16(Bp + (long)(n0 + r_ + srow8) * SKL + (tt) * 64 + scol, \
             lds + (slot) * 16384 + 8192 + r_ * 64); \
    } \
  } while (0)

  const int NT = SKL / 64;              // 32
  ZSTG(0, 0);
  ZSTG(1, 1);
  asm volatile("s_waitcnt vmcnt(4)" ::: "memory");
  asm volatile("s_barrier" ::: "memory");

  for (int t = 0; t < NT; ++t) {
    int cs = t & 1;
    const u16* baseA = lds + cs * 16384;
    const u16* baseB = lds + cs * 16384 + 8192;
    bf16x8 aF[4][2], bF[2][2];
#pragma unroll
    for (int rb = 0; rb < 4; rb++)
#pragma unroll
      for (int ks = 0; ks < 2; ks++) {
        int row = wr * 64 + rb * 16 + fr;
        int cb = (ks * 64 + g * 16) ^ ((row & 7) << 4);
        aF[rb][ks] = *(const bf16x8*)(baseA + row * 64 + (cb >> 1));
      }
#pragma unroll
    for (int jb = 0; jb < 2; jb++)
#pragma unroll
      for (int ks = 0; ks < 2; ks++) {
        int row = wc * 32 + jb * 16 + fr;
        int cb = (ks * 64 + g * 16) ^ ((row & 7) << 4);
        bF[jb][ks] = *(const bf16x8*)(baseB + row * 64 + (cb >> 1));
      }
    asm volatile("s_waitcnt lgkmcnt(0)" ::: "memory");
    __builtin_amdgcn_sched_barrier(0);
    asm volatile("s_barrier" ::: "memory");     // all waves done reading cs
    if (t + 2 < NT) ZSTG(cs, t + 2);            // overwrite cs for t+2
    __builtin_amdgcn_s_setprio(1);
#pragma unroll
    for (int rb = 0; rb < 4; rb++)
#pragma unroll
      for (int jb = 0; jb < 2; jb++)
#pragma unroll
        for (int ks = 0; ks < 2; ks++)
          acc[rb][jb] = __builtin_amdgcn_mfma_f32_16x16x32_bf16(aF[rb][ks], bF[jb][ks], acc[rb][jb], 0, 0, 0);
    __builtin_amdgcn_s_setprio(0);
    if (t + 2 < NT) asm volatile("s_waitcnt vmcnt(4)" ::: "memory");
    else            asm volatile("s_waitcnt vmcnt(0)" ::: "memory");
    asm volatile("s_barrier" ::: "memory");
  }
#undef ZSTG

  int cr = (lane >> 4) * 4, cc = lane & 15;
#pragma unroll
  for (int rb = 0; rb < 4; rb++)
#pragma unroll
    for (int r = 0; r < 4; r++) {
      int q = m0 + wr * 64 + rb * 16 + cr + r;
      float* zrow = Z + ((long)b * SQL + q) * DIM;
#pragma unroll
      for (int jb = 0; jb < 2; jb++)
        zrow[n0 + wc * 32 + jb * 16 + cc] = acc[rb][jb][r];
    }
}

// ---------------- launch ----------------

extern "C" void kernel_launch(void* const* d_in, const int* in_sizes, int n_in,
                              void* d_out, int out_size, void* d_ws, size_t ws_size,
                              hipStream_t stream) {
  const float* Q = (const float*)d_in[0];
  const float* K = (const float*)d_in[1];
  const float* V = (const float*)d_in[2];
  const float* rel = (const float*)d_in[3];
  float* attn = (float*)d_out;                       // [4][2048][2048]
  float* Z = attn + (long)BATCH * SQL * SKL;         // [4][2048][512]

  char* ws = (char*)d_ws;
  u16* Qb   = (u16*)ws;                    //  8 MiB  bf16 Q [b][q][d]
  u16* Kb   = (u16*)(ws + 8388608);        //  8 MiB  bf16 K [b][k][d]
  u16* Vt   = (u16*)(ws + 16777216);       //  8 MiB  bf16 V^T [b][d][k]
  u16* relb = (u16*)(ws + 25165824);       //  288 KiB bf16 rel padded [288][512]
  float* Qrel = (float*)(ws + 25460736);   //  9 MiB  fp32 Qrel [8192][288]
  u16* S    = (u16*)(ws + 34897920);       //  32 MiB bf16 scores/probs [b][q][k]

  prep_mem_kernel<<<12864, 256, 0, stream>>>(Q, K, V, rel, (u16x4*)Qb, (u16x4*)Kb, relb, Vt);
  qrel_kernel<<<dim3(128, 9), 256, 0, stream>>>(Qb, relb, Qrel);
  energy_kernel<<<dim3(8, 8, BATCH), 512, 0, stream>>>(Qb, Kb, S);
  softmax_kernel<<<8192, 256, 0, stream>>>(S, Qrel, attn);
  z_kernel<<<dim3(4, 16, BATCH), 512, 0, stream>>>(S, Vt, Z);
}